// Round 2
// baseline (630.293 us; speedup 1.0000x reference)
//
#include <hip/hip_runtime.h>
#include <hip/hip_bf16.h>

#define NNODES 10000
#define NB 8
#define NF 128
#define NE 160000

// ---------------- preprocessing ----------------

__global__ void k_zero(int* __restrict__ cnt, int* __restrict__ fill) {
    int i = blockIdx.x * blockDim.x + threadIdx.x;
    if (i < NNODES) { cnt[i] = 0; fill[i] = 0; }
}

// edge_index arrives as int32 [2, E] (harness converts integer inputs to int32)
__global__ void k_count(const int* __restrict__ ei, int* __restrict__ cnt) {
    int e = blockIdx.x * blockDim.x + threadIdx.x;
    if (e < NE) atomicAdd(&cnt[ei[NE + e]], 1);
}

__global__ void k_dinv(const int* __restrict__ cnt, float* __restrict__ dinv) {
    int i = blockIdx.x * blockDim.x + threadIdx.x;
    if (i < NNODES) dinv[i] = rsqrtf((float)(cnt[i] + 1));  // +1 self-loop
}

// one-block exclusive scan of cnt[0..N) -> row_ptr[0..N]
__global__ void k_scan(const int* __restrict__ cnt, int* __restrict__ row_ptr) {
    __shared__ int part[1024];
    int t = threadIdx.x;
    const int CH = (NNODES + 1023) / 1024;  // 10
    int lo = t * CH, hi = min(lo + CH, NNODES);
    int s = 0;
    for (int i = lo; i < hi; i++) s += cnt[i];
    part[t] = s;
    __syncthreads();
    // Hillis-Steele inclusive scan over 1024 partials
    for (int off = 1; off < 1024; off <<= 1) {
        int v = (t >= off) ? part[t - off] : 0;
        __syncthreads();
        part[t] += v;
        __syncthreads();
    }
    int base = part[t] - s;  // exclusive prefix for this chunk
    for (int i = lo; i < hi; i++) { row_ptr[i] = base; base += cnt[i]; }
    if (t == 1023) row_ptr[NNODES] = part[1023];
}

__global__ void k_scatter(const int* __restrict__ ei, const int* __restrict__ row_ptr,
                          int* __restrict__ fill, const float* __restrict__ dinv,
                          int* __restrict__ col, float* __restrict__ wgt) {
    int e = blockIdx.x * blockDim.x + threadIdx.x;
    if (e >= NE) return;
    int s = ei[e];
    int d = ei[NE + e];
    int pos = row_ptr[d] + atomicAdd(&fill[d], 1);
    col[pos] = s;
    wgt[pos] = dinv[s] * dinv[d];
}

// ---------------- fp32 matmul: C[M,128] = A[M,128] @ W[128,128] ----------------
// 64 rows/block, 256 threads, 8 rows x 4 cols per thread, A-tile in LDS.
__global__ __launch_bounds__(256) void k_mm128(const float* __restrict__ A,
                                               const float* __restrict__ W,
                                               float* __restrict__ C) {
    __shared__ float xs[64][128];  // 32 KB
    const int row0 = blockIdx.x * 64;
    const int t = threadIdx.x;

    // stage 64x128 A tile (2048 float4, 8 per thread), fully coalesced
    {
        const float4* src = (const float4*)(A + (size_t)row0 * NF);
        float4* dst = (float4*)(&xs[0][0]);
        #pragma unroll
        for (int i = 0; i < 8; i++) dst[t + 256 * i] = src[t + 256 * i];
    }
    __syncthreads();

    const int c0 = (t & 31) * 4;   // 4 consecutive output cols
    const int r0 = (t >> 5) * 8;   // 8 consecutive rows
    float acc[8][4] = {};

    #pragma unroll
    for (int k = 0; k < NF; k += 4) {
        float4 w0 = *(const float4*)(W + (k + 0) * NF + c0);
        float4 w1 = *(const float4*)(W + (k + 1) * NF + c0);
        float4 w2 = *(const float4*)(W + (k + 2) * NF + c0);
        float4 w3 = *(const float4*)(W + (k + 3) * NF + c0);
        #pragma unroll
        for (int r = 0; r < 8; r++) {
            float4 xv = *(const float4*)(&xs[r0 + r][k]);  // wave-uniform -> LDS broadcast
            acc[r][0] += xv.x * w0.x + xv.y * w1.x + xv.z * w2.x + xv.w * w3.x;
            acc[r][1] += xv.x * w0.y + xv.y * w1.y + xv.z * w2.y + xv.w * w3.y;
            acc[r][2] += xv.x * w0.z + xv.y * w1.z + xv.z * w2.z + xv.w * w3.z;
            acc[r][3] += xv.x * w0.w + xv.y * w1.w + xv.z * w2.w + xv.w * w3.w;
        }
    }

    #pragma unroll
    for (int r = 0; r < 8; r++) {
        float4 v = make_float4(acc[r][0], acc[r][1], acc[r][2], acc[r][3]);
        *(float4*)(C + (size_t)(row0 + r0 + r) * NF + c0) = v;
    }
}

// ---------------- aggregation kernels ----------------
// grid: (NNODES, NB), block: 128 threads (one feature each)

__global__ __launch_bounds__(128) void k_agg_relu(const float* __restrict__ h,
                                                  const float* __restrict__ bias,
                                                  const int* __restrict__ row_ptr,
                                                  const int* __restrict__ col,
                                                  const float* __restrict__ wgt,
                                                  const float* __restrict__ dinv,
                                                  float* __restrict__ out) {
    const int i = blockIdx.x;
    const int b = blockIdx.y;
    const int f = threadIdx.x;
    const float* hb = h + (size_t)b * NNODES * NF;
    float di = dinv[i];
    float acc = hb[(size_t)i * NF + f] * di * di;  // self-loop
    int e0 = row_ptr[i], e1 = row_ptr[i + 1];
    for (int e = e0; e < e1; e++) {
        int s = col[e];
        float w = wgt[e];
        acc += hb[(size_t)s * NF + f] * w;
    }
    acc += bias[f];
    out[((size_t)b * NNODES + i) * NF + f] = fmaxf(acc, 0.f);
}

__global__ __launch_bounds__(128) void k_agg_ln(const float* __restrict__ h,
                                                const float* __restrict__ bias,
                                                const int* __restrict__ row_ptr,
                                                const int* __restrict__ col,
                                                const float* __restrict__ wgt,
                                                const float* __restrict__ dinv,
                                                const float* __restrict__ ln_w,
                                                const float* __restrict__ ln_b,
                                                float* __restrict__ out) {
    const int i = blockIdx.x;
    const int b = blockIdx.y;
    const int f = threadIdx.x;
    const float* hb = h + (size_t)b * NNODES * NF;
    float di = dinv[i];
    float acc = hb[(size_t)i * NF + f] * di * di;
    int e0 = row_ptr[i], e1 = row_ptr[i + 1];
    for (int e = e0; e < e1; e++) {
        int s = col[e];
        float w = wgt[e];
        acc += hb[(size_t)s * NF + f] * w;
    }
    acc += bias[f];  // h2 value for feature f

    // LayerNorm over 128 features (2 waves)
    float s1 = acc, s2 = acc * acc;
    #pragma unroll
    for (int m = 1; m < 64; m <<= 1) {
        s1 += __shfl_xor(s1, m);
        s2 += __shfl_xor(s2, m);
    }
    __shared__ float ls1[2], ls2[2];
    int wid = f >> 6;
    if ((f & 63) == 0) { ls1[wid] = s1; ls2[wid] = s2; }
    __syncthreads();
    float t1 = ls1[0] + ls1[1];
    float t2 = ls2[0] + ls2[1];
    float mu = t1 * (1.f / NF);
    float var = t2 * (1.f / NF) - mu * mu;
    float rs = rsqrtf(var + 1e-5f);
    out[((size_t)b * NNODES + i) * NF + f] = (acc - mu) * rs * ln_w[f] + ln_b[f];
}

// ---------------- launch ----------------

extern "C" void kernel_launch(void* const* d_in, const int* in_sizes, int n_in,
                              void* d_out, int out_size, void* d_ws, size_t ws_size,
                              hipStream_t stream) {
    const float* x    = (const float*)d_in[0];
    const int*   ei   = (const int*)d_in[1];   // int32 [2, E] per harness contract
    const float* W1   = (const float*)d_in[2];
    const float* b1   = (const float*)d_in[3];
    const float* W2   = (const float*)d_in[4];
    const float* b2   = (const float*)d_in[5];
    const float* ln_w = (const float*)d_in[6];
    const float* ln_b = (const float*)d_in[7];
    float* out = (float*)d_out;

    // workspace layout (bytes, 16B-aligned sections)
    char* ws = (char*)d_ws;
    int*   cnt     = (int*)(ws + 0);                    // N ints
    int*   fill    = (int*)(ws + 40192);                // N ints
    int*   row_ptr = (int*)(ws + 80384);                // N+1 ints
    float* dinv    = (float*)(ws + 120832);             // N floats
    int*   col     = (int*)(ws + 161024);               // E ints
    float* wgt     = (float*)(ws + 801024);             // E floats
    float* hA      = (float*)(ws + 1441024);            // B*N*128 floats (40.96 MB)

    // ---- build CSR (by dst) + symmetric norm weights ----
    k_zero   <<<(NNODES + 255) / 256, 256, 0, stream>>>(cnt, fill);
    k_count  <<<(NE + 255) / 256, 256, 0, stream>>>(ei, cnt);
    k_dinv   <<<(NNODES + 255) / 256, 256, 0, stream>>>(cnt, dinv);
    k_scan   <<<1, 1024, 0, stream>>>(cnt, row_ptr);
    k_scatter<<<(NE + 255) / 256, 256, 0, stream>>>(ei, row_ptr, fill, dinv, col, wgt);

    // ---- layer 1: h1 = relu(agg(x@W1) + b1)  (h1 lives in d_out temporarily) ----
    dim3 aggGrid(NNODES, NB);
    k_mm128   <<<(NB * NNODES) / 64, 256, 0, stream>>>(x, W1, hA);
    k_agg_relu<<<aggGrid, 128, 0, stream>>>(hA, b1, row_ptr, col, wgt, dinv, out);

    // ---- layer 2: out = LN(agg(h1@W2) + b2) ----
    k_mm128 <<<(NB * NNODES) / 64, 256, 0, stream>>>(out, W2, hA);
    k_agg_ln<<<aggGrid, 128, 0, stream>>>(hA, b2, row_ptr, col, wgt, dinv, ln_w, ln_b, out);
}

// Round 3
// 408.470 us; speedup vs baseline: 1.5431x; 1.5431x over previous
//
#include <hip/hip_runtime.h>
#include <hip/hip_bf16.h>

#define NNODES 10000
#define NB 8
#define NF 128
#define NE 160000

// ---------------- preprocessing ----------------

__global__ void k_zero(int* __restrict__ cnt, int* __restrict__ fill) {
    int i = blockIdx.x * blockDim.x + threadIdx.x;
    if (i < NNODES) { cnt[i] = 0; fill[i] = 0; }
}

// edge_index arrives as int32 [2, E]
__global__ void k_count(const int* __restrict__ ei, int* __restrict__ cnt) {
    int e = blockIdx.x * blockDim.x + threadIdx.x;
    if (e < NE) atomicAdd(&cnt[ei[NE + e]], 1);
}

__global__ void k_dinv(const int* __restrict__ cnt, float* __restrict__ dinv) {
    int i = blockIdx.x * blockDim.x + threadIdx.x;
    if (i < NNODES) dinv[i] = rsqrtf((float)(cnt[i] + 1));  // +1 self-loop
}

// one-block exclusive scan of cnt[0..N) -> row_ptr[0..N]
__global__ void k_scan(const int* __restrict__ cnt, int* __restrict__ row_ptr) {
    __shared__ int part[1024];
    int t = threadIdx.x;
    const int CH = (NNODES + 1023) / 1024;  // 10
    int lo = t * CH, hi = min(lo + CH, NNODES);
    int s = 0;
    for (int i = lo; i < hi; i++) s += cnt[i];
    part[t] = s;
    __syncthreads();
    for (int off = 1; off < 1024; off <<= 1) {
        int v = (t >= off) ? part[t - off] : 0;
        __syncthreads();
        part[t] += v;
        __syncthreads();
    }
    int base = part[t] - s;  // exclusive prefix for this chunk
    for (int i = lo; i < hi; i++) { row_ptr[i] = base; base += cnt[i]; }
    if (t == 1023) row_ptr[NNODES] = part[1023];
}

__global__ void k_scatter(const int* __restrict__ ei, const int* __restrict__ row_ptr,
                          int* __restrict__ fill, const float* __restrict__ dinv,
                          int* __restrict__ col, float* __restrict__ wgt) {
    int e = blockIdx.x * blockDim.x + threadIdx.x;
    if (e >= NE) return;
    int s = ei[e];
    int d = ei[NE + e];
    int pos = row_ptr[d] + atomicAdd(&fill[d], 1);
    col[pos] = s;
    wgt[pos] = dinv[s] * dinv[d];
}

// ---------------- fp32 matmul: C = A[M,128] @ W[128,128], scatter-store to [N, B, 128] ----
// 64 rows/block, 256 threads, 8 rows x 4 cols per thread, A-tile in LDS.
// #pragma unroll 2 on the k-loop: full unroll previously hoisted ~128 float4 W-loads
// -> 256 VGPRs + ~49MB scratch spill traffic (WRITE_SIZE 90MB vs 41MB) -> VALUBusy 1.2%.
__global__ __launch_bounds__(256, 4) void k_mm128(const float* __restrict__ A,
                                                  const float* __restrict__ W,
                                                  float* __restrict__ C_nbf) {
    __shared__ float xs[64][128];  // 32 KB
    const int row0 = blockIdx.x * 64;
    const int t = threadIdx.x;

    {
        const float4* src = (const float4*)(A + (size_t)row0 * NF);
        float4* dst = (float4*)(&xs[0][0]);
        #pragma unroll
        for (int i = 0; i < 8; i++) dst[t + 256 * i] = src[t + 256 * i];
    }
    __syncthreads();

    const int c0 = (t & 31) * 4;   // 4 consecutive output cols
    const int r0 = (t >> 5) * 8;   // 8 consecutive rows
    float acc[8][4] = {};

    #pragma unroll 2
    for (int k = 0; k < NF; k += 4) {
        float4 w0 = *(const float4*)(W + (k + 0) * NF + c0);
        float4 w1 = *(const float4*)(W + (k + 1) * NF + c0);
        float4 w2 = *(const float4*)(W + (k + 2) * NF + c0);
        float4 w3 = *(const float4*)(W + (k + 3) * NF + c0);
        #pragma unroll
        for (int r = 0; r < 8; r++) {
            float4 xv = *(const float4*)(&xs[r0 + r][k]);  // wave-uniform -> LDS broadcast
            acc[r][0] += xv.x * w0.x + xv.y * w1.x + xv.z * w2.x + xv.w * w3.x;
            acc[r][1] += xv.x * w0.y + xv.y * w1.y + xv.z * w2.y + xv.w * w3.y;
            acc[r][2] += xv.x * w0.z + xv.y * w1.z + xv.z * w2.z + xv.w * w3.z;
            acc[r][3] += xv.x * w0.w + xv.y * w1.w + xv.z * w2.w + xv.w * w3.w;
        }
    }

    #pragma unroll
    for (int r = 0; r < 8; r++) {
        int row = row0 + r0 + r;          // row = b*NNODES + n
        int b = row / NNODES;
        int n = row - b * NNODES;
        float4 v = make_float4(acc[r][0], acc[r][1], acc[r][2], acc[r][3]);
        *(float4*)(C_nbf + ((size_t)n * NB + b) * NF + c0) = v;
    }
}

// ---------------- aggregation kernels ----------------
// hN layout: [N, B, 128]. One block per node, 256 threads; thread t handles
// batch b = t>>5, features [ (t&31)*4 .. +4 ). Per edge: one contiguous 4KB
// gather (256 lanes x float4), col/wgt read once. Output in [B, N, 128].

__global__ __launch_bounds__(256) void k_agg_relu(const float4* __restrict__ hN,
                                                  const float4* __restrict__ bias4,
                                                  const int* __restrict__ row_ptr,
                                                  const int* __restrict__ col,
                                                  const float* __restrict__ wgt,
                                                  const float* __restrict__ dinv,
                                                  float4* __restrict__ out4) {
    const int n = blockIdx.x;
    const int t = threadIdx.x;
    const int b = t >> 5;
    const int lane = t & 31;
    const int off = b * 32 + lane;        // float4 offset within a node row (256 float4)

    float di = dinv[n];
    float wself = di * di;
    float4 v = hN[(size_t)n * 256 + off];
    float4 acc;
    acc.x = v.x * wself; acc.y = v.y * wself; acc.z = v.z * wself; acc.w = v.w * wself;

    int e0 = row_ptr[n], e1 = row_ptr[n + 1];
    for (int e = e0; e < e1; ++e) {
        int s = col[e];
        float w = wgt[e];
        float4 u = hN[(size_t)s * 256 + off];
        acc.x += u.x * w; acc.y += u.y * w; acc.z += u.z * w; acc.w += u.w * w;
    }
    float4 bv = bias4[lane];
    acc.x = fmaxf(acc.x + bv.x, 0.f);
    acc.y = fmaxf(acc.y + bv.y, 0.f);
    acc.z = fmaxf(acc.z + bv.z, 0.f);
    acc.w = fmaxf(acc.w + bv.w, 0.f);
    out4[((size_t)b * NNODES + n) * 32 + lane] = acc;
}

__global__ __launch_bounds__(256) void k_agg_ln(const float4* __restrict__ hN,
                                                const float4* __restrict__ bias4,
                                                const int* __restrict__ row_ptr,
                                                const int* __restrict__ col,
                                                const float* __restrict__ wgt,
                                                const float* __restrict__ dinv,
                                                const float4* __restrict__ lnw4,
                                                const float4* __restrict__ lnb4,
                                                float4* __restrict__ out4) {
    const int n = blockIdx.x;
    const int t = threadIdx.x;
    const int b = t >> 5;
    const int lane = t & 31;
    const int off = b * 32 + lane;

    float di = dinv[n];
    float wself = di * di;
    float4 v = hN[(size_t)n * 256 + off];
    float4 acc;
    acc.x = v.x * wself; acc.y = v.y * wself; acc.z = v.z * wself; acc.w = v.w * wself;

    int e0 = row_ptr[n], e1 = row_ptr[n + 1];
    for (int e = e0; e < e1; ++e) {
        int s = col[e];
        float w = wgt[e];
        float4 u = hN[(size_t)s * 256 + off];
        acc.x += u.x * w; acc.y += u.y * w; acc.z += u.z * w; acc.w += u.w * w;
    }
    float4 bv = bias4[lane];
    acc.x += bv.x; acc.y += bv.y; acc.z += bv.z; acc.w += bv.w;

    // LayerNorm over 128 features: each 32-lane group (one batch) reduces via
    // xor-shuffles (mask<32 stays within the group; no LDS, no barrier).
    float s1 = acc.x + acc.y + acc.z + acc.w;
    float s2 = acc.x * acc.x + acc.y * acc.y + acc.z * acc.z + acc.w * acc.w;
    #pragma unroll
    for (int m = 1; m < 32; m <<= 1) {
        s1 += __shfl_xor(s1, m);
        s2 += __shfl_xor(s2, m);
    }
    float mu = s1 * (1.f / NF);
    float var = s2 * (1.f / NF) - mu * mu;
    float rs = rsqrtf(var + 1e-5f);

    float4 gw = lnw4[lane], gb = lnb4[lane];
    float4 o;
    o.x = (acc.x - mu) * rs * gw.x + gb.x;
    o.y = (acc.y - mu) * rs * gw.y + gb.y;
    o.z = (acc.z - mu) * rs * gw.z + gb.z;
    o.w = (acc.w - mu) * rs * gw.w + gb.w;
    out4[((size_t)b * NNODES + n) * 32 + lane] = o;
}

// ---------------- launch ----------------

extern "C" void kernel_launch(void* const* d_in, const int* in_sizes, int n_in,
                              void* d_out, int out_size, void* d_ws, size_t ws_size,
                              hipStream_t stream) {
    const float* x    = (const float*)d_in[0];
    const int*   ei   = (const int*)d_in[1];   // int32 [2, E]
    const float* W1   = (const float*)d_in[2];
    const float* b1   = (const float*)d_in[3];
    const float* W2   = (const float*)d_in[4];
    const float* b2   = (const float*)d_in[5];
    const float* ln_w = (const float*)d_in[6];
    const float* ln_b = (const float*)d_in[7];
    float* out = (float*)d_out;

    // workspace layout (bytes, 16B-aligned sections)
    char* ws = (char*)d_ws;
    int*   cnt     = (int*)(ws + 0);                    // N ints
    int*   fill    = (int*)(ws + 40192);                // N ints
    int*   row_ptr = (int*)(ws + 80384);                // N+1 ints
    float* dinv    = (float*)(ws + 120832);             // N floats
    int*   col     = (int*)(ws + 161024);               // E ints
    float* wgt     = (float*)(ws + 801024);             // E floats
    float* hA      = (float*)(ws + 1441024);            // [N, B, 128] floats (40.96 MB)

    // ---- build CSR (by dst) + symmetric norm weights ----
    k_zero   <<<(NNODES + 255) / 256, 256, 0, stream>>>(cnt, fill);
    k_count  <<<(NE + 255) / 256, 256, 0, stream>>>(ei, cnt);
    k_dinv   <<<(NNODES + 255) / 256, 256, 0, stream>>>(cnt, dinv);
    k_scan   <<<1, 1024, 0, stream>>>(cnt, row_ptr);
    k_scatter<<<(NE + 255) / 256, 256, 0, stream>>>(ei, row_ptr, fill, dinv, col, wgt);

    // ---- layer 1: h1 = relu(agg(x@W1) + b1)  (h1 lives in d_out, [B,N,F]) ----
    k_mm128   <<<(NB * NNODES) / 64, 256, 0, stream>>>(x, W1, hA);
    k_agg_relu<<<NNODES, 256, 0, stream>>>((const float4*)hA, (const float4*)b1,
                                           row_ptr, col, wgt, dinv, (float4*)out);

    // ---- layer 2: out = LN(agg(h1@W2) + b2) ----
    k_mm128 <<<(NB * NNODES) / 64, 256, 0, stream>>>(out, W2, hA);
    k_agg_ln<<<NNODES, 256, 0, stream>>>((const float4*)hA, (const float4*)b2,
                                         row_ptr, col, wgt, dinv,
                                         (const float4*)ln_w, (const float4*)ln_b,
                                         (float4*)out);
}

// Round 5
// 260.808 us; speedup vs baseline: 2.4167x; 1.5662x over previous
//
#include <hip/hip_runtime.h>
#include <hip/hip_bf16.h>

#define NNODES 10000
#define NB 8
#define NF 128
#define NE 160000

typedef __attribute__((ext_vector_type(8))) short  short8;   // 8 bf16 (A/B frag)
typedef __attribute__((ext_vector_type(8))) unsigned short ushort8;
typedef __attribute__((ext_vector_type(4))) float  f32x4;    // MFMA acc

// fp32 -> bf16 (RNE)
__device__ __forceinline__ unsigned short f2b(float f) {
    union { float f; unsigned u; } v; v.f = f;
    unsigned r = v.u + 0x7FFF + ((v.u >> 16) & 1);
    return (unsigned short)(r >> 16);
}
// bf16 bits -> fp32
__device__ __forceinline__ float b2f(unsigned short h) {
    union { unsigned u; float f; } v; v.u = ((unsigned)h) << 16;
    return v.f;
}

// ---------------- preprocessing ----------------

__global__ void k_zero(int* __restrict__ cnt, int* __restrict__ fill) {
    int i = blockIdx.x * blockDim.x + threadIdx.x;
    if (i < NNODES) { cnt[i] = 0; fill[i] = 0; }
}

__global__ void k_count(const int* __restrict__ ei, int* __restrict__ cnt) {
    int e = blockIdx.x * blockDim.x + threadIdx.x;
    if (e < NE) atomicAdd(&cnt[ei[NE + e]], 1);
}

__global__ void k_dinv(const int* __restrict__ cnt, float* __restrict__ dinv) {
    int i = blockIdx.x * blockDim.x + threadIdx.x;
    if (i < NNODES) dinv[i] = rsqrtf((float)(cnt[i] + 1));  // +1 self-loop
}

__global__ void k_scan(const int* __restrict__ cnt, int* __restrict__ row_ptr) {
    __shared__ int part[1024];
    int t = threadIdx.x;
    const int CH = (NNODES + 1023) / 1024;  // 10
    int lo = t * CH, hi = min(lo + CH, NNODES);
    int s = 0;
    for (int i = lo; i < hi; i++) s += cnt[i];
    part[t] = s;
    __syncthreads();
    for (int off = 1; off < 1024; off <<= 1) {
        int v = (t >= off) ? part[t - off] : 0;
        __syncthreads();
        part[t] += v;
        __syncthreads();
    }
    int base = part[t] - s;
    for (int i = lo; i < hi; i++) { row_ptr[i] = base; base += cnt[i]; }
    if (t == 1023) row_ptr[NNODES] = part[1023];
}

__global__ void k_scatter(const int* __restrict__ ei, const int* __restrict__ row_ptr,
                          int* __restrict__ fill, const float* __restrict__ dinv,
                          int* __restrict__ col, float* __restrict__ wgt) {
    int e = blockIdx.x * blockDim.x + threadIdx.x;
    if (e >= NE) return;
    int s = ei[e];
    int d = ei[NE + e];
    int pos = row_ptr[d] + atomicAdd(&fill[d], 1);
    col[pos] = s;
    wgt[pos] = dinv[s] * dinv[d];
}

// W[128,128] fp32 -> Wt[n][k] bf16 (transposed)
__global__ void k_wt(const float* __restrict__ W, unsigned short* __restrict__ Wt) {
    int id = blockIdx.x * 256 + threadIdx.x;   // 16384
    int n = id >> 7, k = id & 127;
    Wt[(size_t)n * 128 + k] = f2b(W[(size_t)k * 128 + n]);
}

// ---------------- bf16 MFMA matmul ----------------
// C = A[80000,128] @ W, output bf16 scattered to [N, B, 128].
// A-op = Wt tiles (M-dim = feature), B-op = activation rows (N-dim = act row):
//   D col=lane&15 -> act row; D row=quad*4+reg -> 4 consecutive features per lane.
// Block: 256 thr = 4 waves; wave = 32 act rows x 64 features; block = 64 rows x 128 feats.
template <bool ABF16>
__global__ __launch_bounds__(256) void k_mm_mfma(const void* __restrict__ Ap,
                                                 const unsigned short* __restrict__ Wt,
                                                 unsigned short* __restrict__ Cn) {
    __shared__ unsigned short wlds[128 * 136];  // +8 bf16 row pad (34 KB)
    const int t = threadIdx.x;
    {   // stage Wt (32 KB) into LDS, 2 threads/row, 64 ushorts (8x ushort8) each
        const int r = t >> 1, h = t & 1;
        const ushort8* src = (const ushort8*)(Wt + r * 128 + h * 64);
        #pragma unroll
        for (int i = 0; i < 8; i++)
            *(ushort8*)(wlds + r * 136 + h * 64 + i * 8) = src[i];
    }
    __syncthreads();

    const int wid = t >> 6, lane = t & 63;
    const int quad = lane >> 4, l16 = lane & 15;
    const int m0 = blockIdx.x * 64 + (wid & 1) * 32;  // activation row base for this wave
    const int nb = (wid >> 1) * 64;                   // feature base
    const int kq = quad * 8;

    f32x4 acc[2][4] = {};

    #pragma unroll
    for (int ks = 0; ks < 128; ks += 32) {
        short8 bf[2];
        #pragma unroll
        for (int mi = 0; mi < 2; mi++) {
            const size_t row = (size_t)(m0 + mi * 16 + l16);
            if constexpr (ABF16) {
                bf[mi] = *(const short8*)((const unsigned short*)Ap + row * 128 + ks + kq);
            } else {
                const float* p = (const float*)Ap + row * 128 + ks + kq;
                float4 u0 = *(const float4*)p;
                float4 u1 = *(const float4*)(p + 4);
                short8 v;
                v[0] = (short)f2b(u0.x); v[1] = (short)f2b(u0.y);
                v[2] = (short)f2b(u0.z); v[3] = (short)f2b(u0.w);
                v[4] = (short)f2b(u1.x); v[5] = (short)f2b(u1.y);
                v[6] = (short)f2b(u1.z); v[7] = (short)f2b(u1.w);
                bf[mi] = v;
            }
        }
        short8 af[4];
        #pragma unroll
        for (int ni = 0; ni < 4; ni++)
            af[ni] = *(const short8*)(wlds + (nb + ni * 16 + l16) * 136 + ks + kq);
        #pragma unroll
        for (int mi = 0; mi < 2; mi++)
            #pragma unroll
            for (int ni = 0; ni < 4; ni++)
                acc[mi][ni] = __builtin_amdgcn_mfma_f32_16x16x32_bf16(
                    af[ni], bf[mi], acc[mi][ni], 0, 0, 0);
    }

    // epilogue: lane holds, per tile, features nb+ni*16+quad*4 .. +3 of act row m0+mi*16+l16
    #pragma unroll
    for (int mi = 0; mi < 2; mi++) {
        int gm = m0 + mi * 16 + l16;        // = b*NNODES + n
        int b = gm / NNODES;
        int n = gm - b * NNODES;
        unsigned short* dst = Cn + ((size_t)n * NB + b) * 128 + nb + quad * 4;
        #pragma unroll
        for (int ni = 0; ni < 4; ni++) {
            ushort4 o;
            o.x = f2b(acc[mi][ni][0]); o.y = f2b(acc[mi][ni][1]);
            o.z = f2b(acc[mi][ni][2]); o.w = f2b(acc[mi][ni][3]);
            *(ushort4*)(dst + ni * 16) = o;
        }
    }
}

// ---------------- aggregation ----------------
// hN: bf16 [N, B, 128]. Block = 1 node, 128 thr; thread: batch b = t>>4,
// 8 feats f0=(t&15)*8 -> 16 B/lane gather, one 2 KB line per edge. fp32 accum.

__global__ __launch_bounds__(128) void k_agg_relu(const unsigned short* __restrict__ hN,
                                                  const float* __restrict__ bias,
                                                  const int* __restrict__ row_ptr,
                                                  const int* __restrict__ col,
                                                  const float* __restrict__ wgt,
                                                  const float* __restrict__ dinv,
                                                  unsigned short* __restrict__ h1b) {
    const int n = blockIdx.x, t = threadIdx.x;
    const int b = t >> 4, f0 = (t & 15) * 8;

    float di = dinv[n];
    float wself = di * di;
    float acc[8];
    {
        ushort8 u = *(const ushort8*)(hN + ((size_t)n * NB + b) * 128 + f0);
        #pragma unroll
        for (int i = 0; i < 8; i++) acc[i] = b2f(u[i]) * wself;
    }
    int e = row_ptr[n], e1 = row_ptr[n + 1];
    for (; e + 4 <= e1; e += 4) {
        int s0 = col[e], s1 = col[e + 1], s2 = col[e + 2], s3 = col[e + 3];
        float w0 = wgt[e], w1 = wgt[e + 1], w2 = wgt[e + 2], w3 = wgt[e + 3];
        ushort8 u0 = *(const ushort8*)(hN + ((size_t)s0 * NB + b) * 128 + f0);
        ushort8 u1 = *(const ushort8*)(hN + ((size_t)s1 * NB + b) * 128 + f0);
        ushort8 u2 = *(const ushort8*)(hN + ((size_t)s2 * NB + b) * 128 + f0);
        ushort8 u3 = *(const ushort8*)(hN + ((size_t)s3 * NB + b) * 128 + f0);
        #pragma unroll
        for (int i = 0; i < 8; i++) {
            acc[i] = fmaf(b2f(u0[i]), w0, acc[i]);
            acc[i] = fmaf(b2f(u1[i]), w1, acc[i]);
            acc[i] = fmaf(b2f(u2[i]), w2, acc[i]);
            acc[i] = fmaf(b2f(u3[i]), w3, acc[i]);
        }
    }
    for (; e < e1; ++e) {
        int s = col[e]; float w = wgt[e];
        ushort8 u = *(const ushort8*)(hN + ((size_t)s * NB + b) * 128 + f0);
        #pragma unroll
        for (int i = 0; i < 8; i++) acc[i] = fmaf(b2f(u[i]), w, acc[i]);
    }
    ushort8 o;
    #pragma unroll
    for (int i = 0; i < 8; i++)
        o[i] = f2b(fmaxf(acc[i] + bias[f0 + i], 0.f));
    *(ushort8*)(h1b + ((size_t)b * NNODES + n) * 128 + f0) = o;
}

__global__ __launch_bounds__(128) void k_agg_ln(const unsigned short* __restrict__ hN,
                                                const float* __restrict__ bias,
                                                const int* __restrict__ row_ptr,
                                                const int* __restrict__ col,
                                                const float* __restrict__ wgt,
                                                const float* __restrict__ dinv,
                                                const float* __restrict__ ln_w,
                                                const float* __restrict__ ln_b,
                                                float* __restrict__ out) {
    const int n = blockIdx.x, t = threadIdx.x;
    const int b = t >> 4, f0 = (t & 15) * 8;

    float di = dinv[n];
    float wself = di * di;
    float acc[8];
    {
        ushort8 u = *(const ushort8*)(hN + ((size_t)n * NB + b) * 128 + f0);
        #pragma unroll
        for (int i = 0; i < 8; i++) acc[i] = b2f(u[i]) * wself;
    }
    int e = row_ptr[n], e1 = row_ptr[n + 1];
    for (; e + 4 <= e1; e += 4) {
        int s0 = col[e], s1 = col[e + 1], s2 = col[e + 2], s3 = col[e + 3];
        float w0 = wgt[e], w1 = wgt[e + 1], w2 = wgt[e + 2], w3 = wgt[e + 3];
        ushort8 u0 = *(const ushort8*)(hN + ((size_t)s0 * NB + b) * 128 + f0);
        ushort8 u1 = *(const ushort8*)(hN + ((size_t)s1 * NB + b) * 128 + f0);
        ushort8 u2 = *(const ushort8*)(hN + ((size_t)s2 * NB + b) * 128 + f0);
        ushort8 u3 = *(const ushort8*)(hN + ((size_t)s3 * NB + b) * 128 + f0);
        #pragma unroll
        for (int i = 0; i < 8; i++) {
            acc[i] = fmaf(b2f(u0[i]), w0, acc[i]);
            acc[i] = fmaf(b2f(u1[i]), w1, acc[i]);
            acc[i] = fmaf(b2f(u2[i]), w2, acc[i]);
            acc[i] = fmaf(b2f(u3[i]), w3, acc[i]);
        }
    }
    for (; e < e1; ++e) {
        int s = col[e]; float w = wgt[e];
        ushort8 u = *(const ushort8*)(hN + ((size_t)s * NB + b) * 128 + f0);
        #pragma unroll
        for (int i = 0; i < 8; i++) acc[i] = fmaf(b2f(u[i]), w, acc[i]);
    }
    #pragma unroll
    for (int i = 0; i < 8; i++) acc[i] += bias[f0 + i];

    // LayerNorm: 16 lanes (one batch) hold all 128 feats; xor-shuffle within group
    float s1 = 0.f, s2 = 0.f;
    #pragma unroll
    for (int i = 0; i < 8; i++) { s1 += acc[i]; s2 += acc[i] * acc[i]; }
    #pragma unroll
    for (int m = 1; m < 16; m <<= 1) {
        s1 += __shfl_xor(s1, m);
        s2 += __shfl_xor(s2, m);
    }
    float mu = s1 * (1.f / NF);
    float var = s2 * (1.f / NF) - mu * mu;
    float rs = rsqrtf(var + 1e-5f);

    float* dst = out + ((size_t)b * NNODES + n) * 128 + f0;
    float4 o0, o1;
    o0.x = (acc[0] - mu) * rs * ln_w[f0 + 0] + ln_b[f0 + 0];
    o0.y = (acc[1] - mu) * rs * ln_w[f0 + 1] + ln_b[f0 + 1];
    o0.z = (acc[2] - mu) * rs * ln_w[f0 + 2] + ln_b[f0 + 2];
    o0.w = (acc[3] - mu) * rs * ln_w[f0 + 3] + ln_b[f0 + 3];
    o1.x = (acc[4] - mu) * rs * ln_w[f0 + 4] + ln_b[f0 + 4];
    o1.y = (acc[5] - mu) * rs * ln_w[f0 + 5] + ln_b[f0 + 5];
    o1.z = (acc[6] - mu) * rs * ln_w[f0 + 6] + ln_b[f0 + 6];
    o1.w = (acc[7] - mu) * rs * ln_w[f0 + 7] + ln_b[f0 + 7];
    *(float4*)dst = o0;
    *(float4*)(dst + 4) = o1;
}

// ---------------- launch ----------------

extern "C" void kernel_launch(void* const* d_in, const int* in_sizes, int n_in,
                              void* d_out, int out_size, void* d_ws, size_t ws_size,
                              hipStream_t stream) {
    const float* x    = (const float*)d_in[0];
    const int*   ei   = (const int*)d_in[1];   // int32 [2, E]
    const float* W1   = (const float*)d_in[2];
    const float* b1   = (const float*)d_in[3];
    const float* W2   = (const float*)d_in[4];
    const float* b2   = (const float*)d_in[5];
    const float* ln_w = (const float*)d_in[6];
    const float* ln_b = (const float*)d_in[7];
    float* out = (float*)d_out;

    // workspace layout (bytes). Wt1/Wt2 reuse cnt/fill regions (dead after scan/scatter).
    char* ws = (char*)d_ws;
    int*            cnt     = (int*)(ws + 0);          // N ints; later Wt1 (32 KB)
    int*            fill    = (int*)(ws + 40192);      // N ints; later Wt2 (32 KB)
    int*            row_ptr = (int*)(ws + 80384);      // N+1 ints
    float*          dinv    = (float*)(ws + 120832);   // N floats
    int*            col     = (int*)(ws + 161024);     // E ints
    float*          wgt     = (float*)(ws + 801024);   // E floats
    unsigned short* hA16    = (unsigned short*)(ws + 1441024);   // [N,B,128] bf16 (20.48 MB)
    unsigned short* h1b     = (unsigned short*)(ws + 21921024);  // [B,N,128] bf16 (20.48 MB)
    unsigned short* Wt1     = (unsigned short*)cnt;
    unsigned short* Wt2     = (unsigned short*)fill;

    // ---- CSR (by dst) + symmetric norm weights ----
    k_zero   <<<(NNODES + 255) / 256, 256, 0, stream>>>(cnt, fill);
    k_count  <<<(NE + 255) / 256, 256, 0, stream>>>(ei, cnt);
    k_dinv   <<<(NNODES + 255) / 256, 256, 0, stream>>>(cnt, dinv);
    k_scan   <<<1, 1024, 0, stream>>>(cnt, row_ptr);
    k_scatter<<<(NE + 255) / 256, 256, 0, stream>>>(ei, row_ptr, fill, dinv, col, wgt);

    // ---- bf16 transposed weights (cnt/fill now dead) ----
    k_wt<<<64, 256, 0, stream>>>(W1, Wt1);
    k_wt<<<64, 256, 0, stream>>>(W2, Wt2);

    // ---- layer 1 ----
    k_mm_mfma<false><<<(NB * NNODES) / 64, 256, 0, stream>>>(x, Wt1, hA16);
    k_agg_relu<<<NNODES, 128, 0, stream>>>(hA16, b1, row_ptr, col, wgt, dinv, h1b);

    // ---- layer 2 ----
    k_mm_mfma<true><<<(NB * NNODES) / 64, 256, 0, stream>>>(h1b, Wt2, hA16);
    k_agg_ln<<<NNODES, 128, 0, stream>>>(hA16, b2, row_ptr, col, wgt, dinv, ln_w, ln_b, out);
}

// Round 7
// 239.981 us; speedup vs baseline: 2.6264x; 1.0868x over previous
//
#include <hip/hip_runtime.h>
#include <hip/hip_bf16.h>

#define NNODES 10000
#define NB 8
#define NF 128
#define NE 160000

typedef __attribute__((ext_vector_type(8))) short  short8;   // 8 bf16 (A/B frag)
typedef __attribute__((ext_vector_type(8))) unsigned short ushort8;
typedef __attribute__((ext_vector_type(4))) float  f32x4;    // MFMA acc

// fp32 -> bf16 (RNE)
__device__ __forceinline__ unsigned short f2b(float f) {
    union { float f; unsigned u; } v; v.f = f;
    unsigned r = v.u + 0x7FFF + ((v.u >> 16) & 1);
    return (unsigned short)(r >> 16);
}
// bf16 bits -> fp32
__device__ __forceinline__ float b2f(unsigned short h) {
    union { unsigned u; float f; } v; v.u = ((unsigned)h) << 16;
    return v.f;
}
__device__ __forceinline__ float b2f_lo(unsigned u) {
    union { unsigned u; float f; } v; v.u = u << 16; return v.f;
}
__device__ __forceinline__ float b2f_hi(unsigned u) {
    union { unsigned u; float f; } v; v.u = u & 0xffff0000u; return v.f;
}

// ---------------- preprocessing ----------------

__global__ void k_zero(int* __restrict__ cnt, int* __restrict__ fill) {
    int i = blockIdx.x * blockDim.x + threadIdx.x;
    if (i < NNODES) { cnt[i] = 0; fill[i] = 0; }
}

__global__ void k_count(const int* __restrict__ ei, int* __restrict__ cnt) {
    int e = blockIdx.x * blockDim.x + threadIdx.x;
    if (e < NE) atomicAdd(&cnt[ei[NE + e]], 1);
}

__global__ void k_dinv(const int* __restrict__ cnt, float* __restrict__ dinv) {
    int i = blockIdx.x * blockDim.x + threadIdx.x;
    if (i < NNODES) dinv[i] = rsqrtf((float)(cnt[i] + 1));  // +1 self-loop
}

__global__ void k_scan(const int* __restrict__ cnt, int* __restrict__ row_ptr) {
    __shared__ int part[1024];
    int t = threadIdx.x;
    const int CH = (NNODES + 1023) / 1024;  // 10
    int lo = t * CH, hi = min(lo + CH, NNODES);
    int s = 0;
    for (int i = lo; i < hi; i++) s += cnt[i];
    part[t] = s;
    __syncthreads();
    for (int off = 1; off < 1024; off <<= 1) {
        int v = (t >= off) ? part[t - off] : 0;
        __syncthreads();
        part[t] += v;
        __syncthreads();
    }
    int base = part[t] - s;
    for (int i = lo; i < hi; i++) { row_ptr[i] = base; base += cnt[i]; }
    if (t == 1023) row_ptr[NNODES] = part[1023];
}

__global__ void k_scatter(const int* __restrict__ ei, const int* __restrict__ row_ptr,
                          int* __restrict__ fill, const float* __restrict__ dinv,
                          int* __restrict__ col, float* __restrict__ wgt) {
    int e = blockIdx.x * blockDim.x + threadIdx.x;
    if (e >= NE) return;
    int s = ei[e];
    int d = ei[NE + e];
    int pos = row_ptr[d] + atomicAdd(&fill[d], 1);
    col[pos] = s;
    wgt[pos] = dinv[s] * dinv[d];
}

// W[128,128] fp32 -> Wt[n][k] bf16 (transposed)
__global__ void k_wt(const float* __restrict__ W, unsigned short* __restrict__ Wt) {
    int id = blockIdx.x * 256 + threadIdx.x;   // 16384
    int n = id >> 7, k = id & 127;
    Wt[(size_t)n * 128 + k] = f2b(W[(size_t)k * 128 + n]);
}

// ---------------- bf16 MFMA matmul ----------------
// C = A[80000,128] @ W, output bf16 to [N, B, 128] (coalesced via LDS staging).
// A-op = Wt tiles (M-dim = feature), B-op = activation rows:
//   D col=lane&15 -> act row; D row=quad*4+reg -> 4 consecutive features per lane.
template <bool ABF16>
__global__ __launch_bounds__(256) void k_mm_mfma(const void* __restrict__ Ap,
                                                 const unsigned short* __restrict__ Wt,
                                                 unsigned short* __restrict__ Cn) {
    __shared__ unsigned short wlds[128 * 136];  // +8 bf16 row pad (34 KB); reused as C-stage
    const int t = threadIdx.x;
    {   // stage Wt (32 KB) into LDS, 2 threads/row, 64 ushorts (8x ushort8) each
        const int r = t >> 1, h = t & 1;
        const ushort8* src = (const ushort8*)(Wt + r * 128 + h * 64);
        #pragma unroll
        for (int i = 0; i < 8; i++)
            *(ushort8*)(wlds + r * 136 + h * 64 + i * 8) = src[i];
    }
    __syncthreads();

    const int wid = t >> 6, lane = t & 63;
    const int quad = lane >> 4, l16 = lane & 15;
    const int m0 = blockIdx.x * 64 + (wid & 1) * 32;  // activation row base for this wave
    const int nb = (wid >> 1) * 64;                   // feature base
    const int kq = quad * 8;

    f32x4 acc[2][4] = {};

    #pragma unroll
    for (int ks = 0; ks < 128; ks += 32) {
        short8 bf[2];
        #pragma unroll
        for (int mi = 0; mi < 2; mi++) {
            const size_t row = (size_t)(m0 + mi * 16 + l16);
            if constexpr (ABF16) {
                bf[mi] = *(const short8*)((const unsigned short*)Ap + row * 128 + ks + kq);
            } else {
                const float* p = (const float*)Ap + row * 128 + ks + kq;
                float4 u0 = *(const float4*)p;
                float4 u1 = *(const float4*)(p + 4);
                short8 v;
                v[0] = (short)f2b(u0.x); v[1] = (short)f2b(u0.y);
                v[2] = (short)f2b(u0.z); v[3] = (short)f2b(u0.w);
                v[4] = (short)f2b(u1.x); v[5] = (short)f2b(u1.y);
                v[6] = (short)f2b(u1.z); v[7] = (short)f2b(u1.w);
                bf[mi] = v;
            }
        }
        short8 af[4];
        #pragma unroll
        for (int ni = 0; ni < 4; ni++)
            af[ni] = *(const short8*)(wlds + (nb + ni * 16 + l16) * 136 + ks + kq);
        #pragma unroll
        for (int mi = 0; mi < 2; mi++)
            #pragma unroll
            for (int ni = 0; ni < 4; ni++)
                acc[mi][ni] = __builtin_amdgcn_mfma_f32_16x16x32_bf16(
                    af[ni], bf[mi], acc[mi][ni], 0, 0, 0);
    }

    // ---- epilogue: stage block's 64x128 bf16 result in LDS, then coalesced stores ----
    __syncthreads();  // all waves done reading W tile; reuse wlds
    {
        const int rbase = (wid & 1) * 32;
        #pragma unroll
        for (int mi = 0; mi < 2; mi++) {
            int rr = rbase + mi * 16 + l16;
            #pragma unroll
            for (int ni = 0; ni < 4; ni++) {
                ushort4 o;
                o.x = f2b(acc[mi][ni][0]); o.y = f2b(acc[mi][ni][1]);
                o.z = f2b(acc[mi][ni][2]); o.w = f2b(acc[mi][ni][3]);
                *(ushort4*)(wlds + rr * 136 + nb + ni * 16 + quad * 4) = o;
            }
        }
    }
    __syncthreads();
    {
        const int r = t >> 2, seg = t & 3;   // 64 rows x 4 segments of 64 B (32 ushorts)
        int gm = blockIdx.x * 64 + r;        // = b*NNODES + n
        int b = gm / NNODES;
        int n = gm - b * NNODES;
        unsigned short* dst = Cn + ((size_t)n * NB + b) * 128 + seg * 32;
        const unsigned short* srow = wlds + r * 136 + seg * 32;
        #pragma unroll
        for (int i = 0; i < 4; i++)
            *(ushort8*)(dst + i * 8) = *(const ushort8*)(srow + i * 8);
    }
}

// ---------------- aggregation ----------------
// hNu: bf16 [N, B, 128] viewed as uint [N*B*64]. One WAVE per (node, batch):
// lane holds features {2*lane, 2*lane+1}; per edge one 256 B contiguous gather.
// b = blockIdx & 7 -> XCD round-robin pins batch b's 2.56 MB slice in one XCD's L2.
// col/wgt/row_ptr via SGPR (wave-uniform) loads; outputs via nontemporal stores.

__global__ __launch_bounds__(256) void k_agg_relu(const unsigned int* __restrict__ hNu,
                                                  const float* __restrict__ bias,
                                                  const int* __restrict__ row_ptr,
                                                  const int* __restrict__ col,
                                                  const float* __restrict__ wgt,
                                                  const float* __restrict__ dinv,
                                                  unsigned int* __restrict__ h1u) {
    const int t = threadIdx.x;
    const int b = blockIdx.x & 7;
    const int g = blockIdx.x >> 3;
    const int wid = __builtin_amdgcn_readfirstlane(t >> 6);
    const int lane = t & 63;
    const int n = g * 4 + wid;

    const unsigned int* base = hNu + (size_t)b * 64 + lane;  // + s*512
    float di = dinv[n];
    float wself = di * di;
    unsigned int u = base[(size_t)n * 512];
    float a0 = b2f_lo(u) * wself;
    float a1 = b2f_hi(u) * wself;

    int e = row_ptr[n], e1 = row_ptr[n + 1];
    for (; e + 4 <= e1; e += 4) {
        int s0 = col[e], s1 = col[e + 1], s2 = col[e + 2], s3 = col[e + 3];
        float w0 = wgt[e], w1 = wgt[e + 1], w2 = wgt[e + 2], w3 = wgt[e + 3];
        unsigned int u0 = base[(size_t)s0 * 512];
        unsigned int u1 = base[(size_t)s1 * 512];
        unsigned int u2 = base[(size_t)s2 * 512];
        unsigned int u3 = base[(size_t)s3 * 512];
        a0 = fmaf(b2f_lo(u0), w0, a0); a1 = fmaf(b2f_hi(u0), w0, a1);
        a0 = fmaf(b2f_lo(u1), w1, a0); a1 = fmaf(b2f_hi(u1), w1, a1);
        a0 = fmaf(b2f_lo(u2), w2, a0); a1 = fmaf(b2f_hi(u2), w2, a1);
        a0 = fmaf(b2f_lo(u3), w3, a0); a1 = fmaf(b2f_hi(u3), w3, a1);
    }
    for (; e < e1; ++e) {
        int s = col[e]; float w = wgt[e];
        unsigned int uu = base[(size_t)s * 512];
        a0 = fmaf(b2f_lo(uu), w, a0); a1 = fmaf(b2f_hi(uu), w, a1);
    }
    a0 = fmaxf(a0 + bias[lane * 2], 0.f);
    a1 = fmaxf(a1 + bias[lane * 2 + 1], 0.f);
    unsigned int o = (unsigned int)f2b(a0) | ((unsigned int)f2b(a1) << 16);
    __builtin_nontemporal_store(o, &h1u[((size_t)b * NNODES + n) * 64 + lane]);
}

__global__ __launch_bounds__(256) void k_agg_ln(const unsigned int* __restrict__ hNu,
                                                const float* __restrict__ bias,
                                                const int* __restrict__ row_ptr,
                                                const int* __restrict__ col,
                                                const float* __restrict__ wgt,
                                                const float* __restrict__ dinv,
                                                const float* __restrict__ ln_w,
                                                const float* __restrict__ ln_b,
                                                float* __restrict__ out) {
    const int t = threadIdx.x;
    const int b = blockIdx.x & 7;
    const int g = blockIdx.x >> 3;
    const int wid = __builtin_amdgcn_readfirstlane(t >> 6);
    const int lane = t & 63;
    const int n = g * 4 + wid;

    const unsigned int* base = hNu + (size_t)b * 64 + lane;
    float di = dinv[n];
    float wself = di * di;
    unsigned int u = base[(size_t)n * 512];
    float a0 = b2f_lo(u) * wself;
    float a1 = b2f_hi(u) * wself;

    int e = row_ptr[n], e1 = row_ptr[n + 1];
    for (; e + 4 <= e1; e += 4) {
        int s0 = col[e], s1 = col[e + 1], s2 = col[e + 2], s3 = col[e + 3];
        float w0 = wgt[e], w1 = wgt[e + 1], w2 = wgt[e + 2], w3 = wgt[e + 3];
        unsigned int u0 = base[(size_t)s0 * 512];
        unsigned int u1 = base[(size_t)s1 * 512];
        unsigned int u2 = base[(size_t)s2 * 512];
        unsigned int u3 = base[(size_t)s3 * 512];
        a0 = fmaf(b2f_lo(u0), w0, a0); a1 = fmaf(b2f_hi(u0), w0, a1);
        a0 = fmaf(b2f_lo(u1), w1, a0); a1 = fmaf(b2f_hi(u1), w1, a1);
        a0 = fmaf(b2f_lo(u2), w2, a0); a1 = fmaf(b2f_hi(u2), w2, a1);
        a0 = fmaf(b2f_lo(u3), w3, a0); a1 = fmaf(b2f_hi(u3), w3, a1);
    }
    for (; e < e1; ++e) {
        int s = col[e]; float w = wgt[e];
        unsigned int uu = base[(size_t)s * 512];
        a0 = fmaf(b2f_lo(uu), w, a0); a1 = fmaf(b2f_hi(uu), w, a1);
    }
    a0 += bias[lane * 2];
    a1 += bias[lane * 2 + 1];

    // LayerNorm over 128 feats spread across the 64-lane wave (2/lane)
    float s1 = a0 + a1;
    float s2 = a0 * a0 + a1 * a1;
    #pragma unroll
    for (int m = 1; m < 64; m <<= 1) {
        s1 += __shfl_xor(s1, m);
        s2 += __shfl_xor(s2, m);
    }
    float mu = s1 * (1.f / NF);
    float var = s2 * (1.f / NF) - mu * mu;
    float rs = rsqrtf(var + 1e-5f);

    float o0 = (a0 - mu) * rs * ln_w[lane * 2] + ln_b[lane * 2];
    float o1 = (a1 - mu) * rs * ln_w[lane * 2 + 1] + ln_b[lane * 2 + 1];
    float* dst = out + ((size_t)b * NNODES + n) * 128 + lane * 2;
    __builtin_nontemporal_store(o0, dst);
    __builtin_nontemporal_store(o1, dst + 1);
}

// ---------------- launch ----------------

extern "C" void kernel_launch(void* const* d_in, const int* in_sizes, int n_in,
                              void* d_out, int out_size, void* d_ws, size_t ws_size,
                              hipStream_t stream) {
    const float* x    = (const float*)d_in[0];
    const int*   ei   = (const int*)d_in[1];   // int32 [2, E]
    const float* W1   = (const float*)d_in[2];
    const float* b1   = (const float*)d_in[3];
    const float* W2   = (const float*)d_in[4];
    const float* b2   = (const float*)d_in[5];
    const float* ln_w = (const float*)d_in[6];
    const float* ln_b = (const float*)d_in[7];
    float* out = (float*)d_out;

    // workspace layout (bytes). Wt1/Wt2 reuse cnt/fill regions (dead after scan/scatter).
    char* ws = (char*)d_ws;
    int*            cnt     = (int*)(ws + 0);          // N ints; later Wt1 (32 KB)
    int*            fill    = (int*)(ws + 40192);      // N ints; later Wt2 (32 KB)
    int*            row_ptr = (int*)(ws + 80384);      // N+1 ints
    float*          dinv    = (float*)(ws + 120832);   // N floats
    int*            col     = (int*)(ws + 161024);     // E ints
    float*          wgt     = (float*)(ws + 801024);   // E floats
    unsigned short* hA16    = (unsigned short*)(ws + 1441024);   // [N,B,128] bf16 (20.48 MB)
    unsigned short* h1b     = (unsigned short*)(ws + 21921024);  // [B,N,128] bf16 (20.48 MB)
    unsigned short* Wt1     = (unsigned short*)cnt;
    unsigned short* Wt2     = (unsigned short*)fill;

    // ---- CSR (by dst) + symmetric norm weights ----
    k_zero   <<<(NNODES + 255) / 256, 256, 0, stream>>>(cnt, fill);
    k_count  <<<(NE + 255) / 256, 256, 0, stream>>>(ei, cnt);
    k_dinv   <<<(NNODES + 255) / 256, 256, 0, stream>>>(cnt, dinv);
    k_scan   <<<1, 1024, 0, stream>>>(cnt, row_ptr);
    k_scatter<<<(NE + 255) / 256, 256, 0, stream>>>(ei, row_ptr, fill, dinv, col, wgt);

    // ---- bf16 transposed weights (cnt/fill now dead) ----
    k_wt<<<64, 256, 0, stream>>>(W1, Wt1);
    k_wt<<<64, 256, 0, stream>>>(W2, Wt2);

    // ---- layer 1 ----
    k_mm_mfma<false><<<(NB * NNODES) / 64, 256, 0, stream>>>(x, Wt1, hA16);
    k_agg_relu<<<(NNODES / 4) * NB, 256, 0, stream>>>((const unsigned int*)hA16, b1,
                                                      row_ptr, col, wgt, dinv,
                                                      (unsigned int*)h1b);

    // ---- layer 2 ----
    k_mm_mfma<true><<<(NB * NNODES) / 64, 256, 0, stream>>>(h1b, Wt2, hA16);
    k_agg_ln<<<(NNODES / 4) * NB, 256, 0, stream>>>((const unsigned int*)hA16, b2,
                                                    row_ptr, col, wgt, dinv,
                                                    ln_w, ln_b, out);
}

// Round 8
// 231.618 us; speedup vs baseline: 2.7213x; 1.0361x over previous
//
#include <hip/hip_runtime.h>
#include <hip/hip_bf16.h>

#define NNODES 10000
#define NB 8
#define NF 128
#define NE 160000

typedef __attribute__((ext_vector_type(8))) short  short8;   // 8 bf16 (A/B frag)
typedef __attribute__((ext_vector_type(8))) unsigned short ushort8;
typedef __attribute__((ext_vector_type(4))) float  f32x4;    // MFMA acc

// fp32 -> bf16 (RNE) scalar
__device__ __forceinline__ unsigned short f2b(float f) {
    union { float f; unsigned u; } v; v.f = f;
    unsigned r = v.u + 0x7FFF + ((v.u >> 16) & 1);
    return (unsigned short)(r >> 16);
}
// packed pair fp32 -> bf16x2 (lowers to v_cvt_pk_bf16_f32 on gfx950)
__device__ __forceinline__ unsigned int f2b2(float a, float b) {
    union { __hip_bfloat162 h; unsigned int u; } v;
    v.h = __float22bfloat162_rn(make_float2(a, b));
    return v.u;
}
__device__ __forceinline__ float b2f_lo(unsigned u) {
    union { unsigned u; float f; } v; v.u = u << 16; return v.f;
}
__device__ __forceinline__ float b2f_hi(unsigned u) {
    union { unsigned u; float f; } v; v.u = u & 0xffff0000u; return v.f;
}

// ---------------- preprocessing ----------------

__global__ void k_zero(int* __restrict__ cnt, int* __restrict__ fill) {
    int i = blockIdx.x * blockDim.x + threadIdx.x;
    if (i < NNODES) cnt[i] = 0;
    else if (i < 2 * NNODES) fill[i - NNODES] = 0;
}

__global__ void k_count(const int* __restrict__ ei, int* __restrict__ cnt) {
    int e = blockIdx.x * blockDim.x + threadIdx.x;
    if (e < NE) atomicAdd(&cnt[ei[NE + e]], 1);
}

// one-block scan of cnt -> row_ptr, plus dinv = rsqrt(deg+1)
__global__ void k_scan(const int* __restrict__ cnt, int* __restrict__ row_ptr,
                       float* __restrict__ dinv) {
    __shared__ int part[1024];
    int t = threadIdx.x;
    const int CH = (NNODES + 1023) / 1024;  // 10
    int lo = t * CH, hi = min(lo + CH, NNODES);
    int s = 0;
    for (int i = lo; i < hi; i++) {
        int c = cnt[i];
        dinv[i] = rsqrtf((float)(c + 1));
        s += c;
    }
    part[t] = s;
    __syncthreads();
    for (int off = 1; off < 1024; off <<= 1) {
        int v = (t >= off) ? part[t - off] : 0;
        __syncthreads();
        part[t] += v;
        __syncthreads();
    }
    int base = part[t] - s;
    for (int i = lo; i < hi; i++) { row_ptr[i] = base; base += cnt[i]; }
    if (t == 1023) row_ptr[NNODES] = part[1023];
}

// CSR scatter; edge[pos] = {src, bits(w)}
__global__ void k_scatter(const int* __restrict__ ei, const int* __restrict__ row_ptr,
                          int* __restrict__ fill, const float* __restrict__ dinv,
                          uint2* __restrict__ edge) {
    int e = blockIdx.x * blockDim.x + threadIdx.x;
    if (e >= NE) return;
    int s = ei[e];
    int d = ei[NE + e];
    int pos = row_ptr[d] + atomicAdd(&fill[d], 1);
    edge[pos] = make_uint2((unsigned)s, __float_as_uint(dinv[s] * dinv[d]));
}

// both W -> Wt bf16 transposed (runs AFTER scan/scatter: Wt alias cnt/fill)
__global__ void k_wt2(const float* __restrict__ W1, unsigned short* __restrict__ Wt1,
                      const float* __restrict__ W2, unsigned short* __restrict__ Wt2) {
    int bid = blockIdx.x;
    const float* W = (bid < 64) ? W1 : W2;
    unsigned short* Wt = (bid < 64) ? Wt1 : Wt2;
    int id = (bid & 63) * 256 + threadIdx.x;   // 16384
    int n = id >> 7, k = id & 127;
    Wt[(size_t)n * 128 + k] = f2b(W[(size_t)k * 128 + n]);
}

// ---------------- bf16 MFMA matmul ----------------
// C = A[80000,128] @ W, bf16 out to [N, B, 128], 128 rows/block.
// A-op = Wt tiles (M-dim = feature), B-op = activation rows:
//   D col=lane&15 -> act row; D row=quad*4+reg -> 4 consecutive features/lane.
template <bool ABF16>
__global__ __launch_bounds__(256) void k_mm_mfma(const void* __restrict__ Ap,
                                                 const unsigned short* __restrict__ Wt,
                                                 unsigned short* __restrict__ Cn) {
    __shared__ unsigned short wlds[128 * 136];  // +8 pad (34.8 KB); reused as C-stage
    const int t = threadIdx.x;
    {   // stage Wt (32 KB), 2 threads/row, 64 ushorts each
        const int r = t >> 1, h = t & 1;
        const ushort8* src = (const ushort8*)(Wt + r * 128 + h * 64);
        #pragma unroll
        for (int i = 0; i < 8; i++)
            *(ushort8*)(wlds + r * 136 + h * 64 + i * 8) = src[i];
    }
    __syncthreads();

    const int wid = t >> 6, lane = t & 63;
    const int quad = lane >> 4, l16 = lane & 15;
    const int m0 = blockIdx.x * 128 + (wid & 1) * 64;  // act row base for this wave
    const int nb = (wid >> 1) * 64;                    // feature base
    const int kq = quad * 8;

    f32x4 acc[4][4] = {};

    #pragma unroll
    for (int ks = 0; ks < 128; ks += 32) {
        short8 bf[4];
        #pragma unroll
        for (int mi = 0; mi < 4; mi++) {
            const size_t row = (size_t)(m0 + mi * 16 + l16);
            if constexpr (ABF16) {
                bf[mi] = *(const short8*)((const unsigned short*)Ap + row * 128 + ks + kq);
            } else {
                const float* p = (const float*)Ap + row * 128 + ks + kq;
                float4 u0 = *(const float4*)p;
                float4 u1 = *(const float4*)(p + 4);
                union { uint4 u4; short8 s8; } cv;
                cv.u4.x = f2b2(u0.x, u0.y); cv.u4.y = f2b2(u0.z, u0.w);
                cv.u4.z = f2b2(u1.x, u1.y); cv.u4.w = f2b2(u1.z, u1.w);
                bf[mi] = cv.s8;
            }
        }
        short8 af[4];
        #pragma unroll
        for (int ni = 0; ni < 4; ni++)
            af[ni] = *(const short8*)(wlds + (nb + ni * 16 + l16) * 136 + ks + kq);
        #pragma unroll
        for (int mi = 0; mi < 4; mi++)
            #pragma unroll
            for (int ni = 0; ni < 4; ni++)
                acc[mi][ni] = __builtin_amdgcn_mfma_f32_16x16x32_bf16(
                    af[ni], bf[mi], acc[mi][ni], 0, 0, 0);
    }

    // ---- epilogue: stage 128x128 bf16 tile in LDS, coalesced stores ----
    __syncthreads();  // done reading W tile; reuse wlds
    {
        const int rbase = (wid & 1) * 64;
        #pragma unroll
        for (int mi = 0; mi < 4; mi++) {
            int rr = rbase + mi * 16 + l16;
            #pragma unroll
            for (int ni = 0; ni < 4; ni++) {
                uint2 p;
                p.x = f2b2(acc[mi][ni][0], acc[mi][ni][1]);
                p.y = f2b2(acc[mi][ni][2], acc[mi][ni][3]);
                *(uint2*)(wlds + rr * 136 + nb + ni * 16 + quad * 4) = p;
            }
        }
    }
    __syncthreads();
    {
        const int r = t >> 1, h = t & 1;     // 128 rows x 2 halves of 128 B
        int gm = blockIdx.x * 128 + r;       // = b*NNODES + n
        int b = gm / NNODES;
        int n = gm - b * NNODES;
        unsigned short* dst = Cn + ((size_t)n * NB + b) * 128 + h * 64;
        const unsigned short* srow = wlds + r * 136 + h * 64;
        #pragma unroll
        for (int i = 0; i < 8; i++)
            *(ushort8*)(dst + i * 8) = *(const ushort8*)(srow + i * 8);
    }
}

// ---------------- aggregation ----------------
// hNu: bf16 [N, B, 128] viewed as uint. One WAVE per (node, batch); lane holds
// feats {2*lane, 2*lane+1}; per edge one 256 B contiguous gather.
// b = blockIdx & 7 -> XCD round-robin pins batch b's 2.56 MB slice in its L2.
// Edges packed (col,wgt) -> one scalar load each; 8 gathers in flight.

__global__ __launch_bounds__(256) void k_agg_relu(const unsigned int* __restrict__ hNu,
                                                  const float* __restrict__ bias,
                                                  const int* __restrict__ row_ptr,
                                                  const uint2* __restrict__ edge,
                                                  const float* __restrict__ dinv,
                                                  unsigned int* __restrict__ h1u) {
    const int t = threadIdx.x;
    const int b = blockIdx.x & 7;
    const int g = blockIdx.x >> 3;
    const int wid = __builtin_amdgcn_readfirstlane(t >> 6);
    const int lane = t & 63;
    const int n = g * 4 + wid;

    const unsigned int* base = hNu + (size_t)b * 64 + lane;  // + s*512
    float di = dinv[n];
    float wself = di * di;
    unsigned int u = base[(size_t)n * 512];
    float a0 = b2f_lo(u) * wself;
    float a1 = b2f_hi(u) * wself;

    int e = row_ptr[n], e1 = row_ptr[n + 1];
    for (; e + 8 <= e1; e += 8) {
        uint2 E[8];
        #pragma unroll
        for (int j = 0; j < 8; j++) E[j] = edge[e + j];
        unsigned int U[8];
        #pragma unroll
        for (int j = 0; j < 8; j++) U[j] = base[(size_t)E[j].x * 512];
        #pragma unroll
        for (int j = 0; j < 8; j++) {
            float w = __uint_as_float(E[j].y);
            a0 = fmaf(b2f_lo(U[j]), w, a0);
            a1 = fmaf(b2f_hi(U[j]), w, a1);
        }
    }
    for (; e + 4 <= e1; e += 4) {
        uint2 E[4];
        #pragma unroll
        for (int j = 0; j < 4; j++) E[j] = edge[e + j];
        unsigned int U[4];
        #pragma unroll
        for (int j = 0; j < 4; j++) U[j] = base[(size_t)E[j].x * 512];
        #pragma unroll
        for (int j = 0; j < 4; j++) {
            float w = __uint_as_float(E[j].y);
            a0 = fmaf(b2f_lo(U[j]), w, a0);
            a1 = fmaf(b2f_hi(U[j]), w, a1);
        }
    }
    for (; e < e1; ++e) {
        uint2 E = edge[e];
        float w = __uint_as_float(E.y);
        unsigned int uu = base[(size_t)E.x * 512];
        a0 = fmaf(b2f_lo(uu), w, a0);
        a1 = fmaf(b2f_hi(uu), w, a1);
    }
    a0 = fmaxf(a0 + bias[lane * 2], 0.f);
    a1 = fmaxf(a1 + bias[lane * 2 + 1], 0.f);
    __builtin_nontemporal_store(f2b2(a0, a1), &h1u[((size_t)b * NNODES + n) * 64 + lane]);
}

__global__ __launch_bounds__(256) void k_agg_ln(const unsigned int* __restrict__ hNu,
                                                const float* __restrict__ bias,
                                                const int* __restrict__ row_ptr,
                                                const uint2* __restrict__ edge,
                                                const float* __restrict__ dinv,
                                                const float* __restrict__ ln_w,
                                                const float* __restrict__ ln_b,
                                                float* __restrict__ out) {
    const int t = threadIdx.x;
    const int b = blockIdx.x & 7;
    const int g = blockIdx.x >> 3;
    const int wid = __builtin_amdgcn_readfirstlane(t >> 6);
    const int lane = t & 63;
    const int n = g * 4 + wid;

    const unsigned int* base = hNu + (size_t)b * 64 + lane;
    float di = dinv[n];
    float wself = di * di;
    unsigned int u = base[(size_t)n * 512];
    float a0 = b2f_lo(u) * wself;
    float a1 = b2f_hi(u) * wself;

    int e = row_ptr[n], e1 = row_ptr[n + 1];
    for (; e + 8 <= e1; e += 8) {
        uint2 E[8];
        #pragma unroll
        for (int j = 0; j < 8; j++) E[j] = edge[e + j];
        unsigned int U[8];
        #pragma unroll
        for (int j = 0; j < 8; j++) U[j] = base[(size_t)E[j].x * 512];
        #pragma unroll
        for (int j = 0; j < 8; j++) {
            float w = __uint_as_float(E[j].y);
            a0 = fmaf(b2f_lo(U[j]), w, a0);
            a1 = fmaf(b2f_hi(U[j]), w, a1);
        }
    }
    for (; e + 4 <= e1; e += 4) {
        uint2 E[4];
        #pragma unroll
        for (int j = 0; j < 4; j++) E[j] = edge[e + j];
        unsigned int U[4];
        #pragma unroll
        for (int j = 0; j < 4; j++) U[j] = base[(size_t)E[j].x * 512];
        #pragma unroll
        for (int j = 0; j < 4; j++) {
            float w = __uint_as_float(E[j].y);
            a0 = fmaf(b2f_lo(U[j]), w, a0);
            a1 = fmaf(b2f_hi(U[j]), w, a1);
        }
    }
    for (; e < e1; ++e) {
        uint2 E = edge[e];
        float w = __uint_as_float(E.y);
        unsigned int uu = base[(size_t)E.x * 512];
        a0 = fmaf(b2f_lo(uu), w, a0);
        a1 = fmaf(b2f_hi(uu), w, a1);
    }
    a0 += bias[lane * 2];
    a1 += bias[lane * 2 + 1];

    // LayerNorm over 128 feats spread across the 64-lane wave (2/lane)
    float s1 = a0 + a1;
    float s2 = a0 * a0 + a1 * a1;
    #pragma unroll
    for (int m = 1; m < 64; m <<= 1) {
        s1 += __shfl_xor(s1, m);
        s2 += __shfl_xor(s2, m);
    }
    float mu = s1 * (1.f / NF);
    float var = s2 * (1.f / NF) - mu * mu;
    float rs = rsqrtf(var + 1e-5f);

    float o0 = (a0 - mu) * rs * ln_w[lane * 2] + ln_b[lane * 2];
    float o1 = (a1 - mu) * rs * ln_w[lane * 2 + 1] + ln_b[lane * 2 + 1];
    float* dst = out + ((size_t)b * NNODES + n) * 128 + lane * 2;
    __builtin_nontemporal_store(o0, dst);
    __builtin_nontemporal_store(o1, dst + 1);
}

// ---------------- launch ----------------

extern "C" void kernel_launch(void* const* d_in, const int* in_sizes, int n_in,
                              void* d_out, int out_size, void* d_ws, size_t ws_size,
                              hipStream_t stream) {
    const float* x    = (const float*)d_in[0];
    const int*   ei   = (const int*)d_in[1];   // int32 [2, E]
    const float* W1   = (const float*)d_in[2];
    const float* b1   = (const float*)d_in[3];
    const float* W2   = (const float*)d_in[4];
    const float* b2   = (const float*)d_in[5];
    const float* ln_w = (const float*)d_in[6];
    const float* ln_b = (const float*)d_in[7];
    float* out = (float*)d_out;

    // workspace layout. Wt1/Wt2 alias cnt/fill (dead after scan/scatter; k_wt2 runs after).
    char* ws = (char*)d_ws;
    int*            cnt     = (int*)(ws + 0);          // N ints; later Wt1 (32 KB)
    int*            fill    = (int*)(ws + 40192);      // N ints; later Wt2 (32 KB)
    int*            row_ptr = (int*)(ws + 80384);      // N+1 ints
    float*          dinv    = (float*)(ws + 120832);   // N floats
    uint2*          edge    = (uint2*)(ws + 161024);   // E uint2 (1.28 MB)
    unsigned short* hA16    = (unsigned short*)(ws + 1441024);   // [N,B,128] bf16 (20.48 MB)
    unsigned short* h1b     = (unsigned short*)(ws + 21921024);  // [B,N,128] bf16 (20.48 MB)
    unsigned short* Wt1     = (unsigned short*)cnt;
    unsigned short* Wt2     = (unsigned short*)fill;

    // ---- CSR (by dst) + symmetric norm weights ----
    k_zero   <<<(2 * NNODES + 255) / 256, 256, 0, stream>>>(cnt, fill);
    k_count  <<<(NE + 255) / 256, 256, 0, stream>>>(ei, cnt);
    k_scan   <<<1, 1024, 0, stream>>>(cnt, row_ptr, dinv);
    k_scatter<<<(NE + 255) / 256, 256, 0, stream>>>(ei, row_ptr, fill, dinv, edge);
    k_wt2    <<<128, 256, 0, stream>>>(W1, Wt1, W2, Wt2);

    // ---- layer 1 ----
    k_mm_mfma<false><<<(NB * NNODES) / 128, 256, 0, stream>>>(x, Wt1, hA16);
    k_agg_relu<<<(NNODES / 4) * NB, 256, 0, stream>>>((const unsigned int*)hA16, b1,
                                                      row_ptr, edge, dinv,
                                                      (unsigned int*)h1b);

    // ---- layer 2 ----
    k_mm_mfma<true><<<(NB * NNODES) / 128, 256, 0, stream>>>(h1b, Wt2, hA16);
    k_agg_ln<<<(NNODES / 4) * NB, 256, 0, stream>>>((const unsigned int*)hA16, b2,
                                                    row_ptr, edge, dinv,
                                                    ln_w, ln_b, out);
}

// Round 9
// 230.014 us; speedup vs baseline: 2.7402x; 1.0070x over previous
//
#include <hip/hip_runtime.h>
#include <hip/hip_bf16.h>

#define NNODES 10000
#define NB 8
#define NF 128
#define NE 160000

typedef __attribute__((ext_vector_type(8))) short  short8;   // 8 bf16 (A/B frag)
typedef __attribute__((ext_vector_type(8))) unsigned short ushort8;
typedef __attribute__((ext_vector_type(4))) float  f32x4;    // MFMA acc

// fp32 -> bf16 (RNE) scalar
__device__ __forceinline__ unsigned short f2b(float f) {
    union { float f; unsigned u; } v; v.f = f;
    unsigned r = v.u + 0x7FFF + ((v.u >> 16) & 1);
    return (unsigned short)(r >> 16);
}
// packed pair fp32 -> bf16x2 (v_cvt_pk_bf16_f32)
__device__ __forceinline__ unsigned int f2b2(float a, float b) {
    union { __hip_bfloat162 h; unsigned int u; } v;
    v.h = __float22bfloat162_rn(make_float2(a, b));
    return v.u;
}
__device__ __forceinline__ float b2f_lo(unsigned u) {
    union { unsigned u; float f; } v; v.u = u << 16; return v.f;
}
__device__ __forceinline__ float b2f_hi(unsigned u) {
    union { unsigned u; float f; } v; v.u = u & 0xffff0000u; return v.f;
}

// ---------------- preprocessing ----------------

__global__ void k_zero(int* __restrict__ cnt, int* __restrict__ fill) {
    int i = blockIdx.x * blockDim.x + threadIdx.x;
    if (i < NNODES) cnt[i] = 0;
    else if (i < 2 * NNODES) fill[i - NNODES] = 0;
}

__global__ void k_count(const int* __restrict__ ei, int* __restrict__ cnt) {
    int e = blockIdx.x * blockDim.x + threadIdx.x;
    if (e < NE) atomicAdd(&cnt[ei[NE + e]], 1);
}

// one-block scan of cnt -> row_ptr, plus dinv = rsqrt(deg+1)
__global__ void k_scan(const int* __restrict__ cnt, int* __restrict__ row_ptr,
                       float* __restrict__ dinv) {
    __shared__ int part[1024];
    int t = threadIdx.x;
    const int CH = (NNODES + 1023) / 1024;  // 10
    int lo = t * CH, hi = min(lo + CH, NNODES);
    int s = 0;
    for (int i = lo; i < hi; i++) {
        int c = cnt[i];
        dinv[i] = rsqrtf((float)(c + 1));
        s += c;
    }
    part[t] = s;
    __syncthreads();
    for (int off = 1; off < 1024; off <<= 1) {
        int v = (t >= off) ? part[t - off] : 0;
        __syncthreads();
        part[t] += v;
        __syncthreads();
    }
    int base = part[t] - s;
    for (int i = lo; i < hi; i++) { row_ptr[i] = base; base += cnt[i]; }
    if (t == 1023) row_ptr[NNODES] = part[1023];
}

// CSR scatter; edge[pos] = src(16b) | bf16(w) << 16   (4 B per edge)
__global__ void k_scatter(const int* __restrict__ ei, const int* __restrict__ row_ptr,
                          int* __restrict__ fill, const float* __restrict__ dinv,
                          unsigned int* __restrict__ edge) {
    int e = blockIdx.x * blockDim.x + threadIdx.x;
    if (e >= NE) return;
    int s = ei[e];
    int d = ei[NE + e];
    int pos = row_ptr[d] + atomicAdd(&fill[d], 1);
    edge[pos] = (unsigned)s | ((unsigned)f2b(dinv[s] * dinv[d]) << 16);
}

// both W -> Wt bf16 transposed (runs AFTER scan/scatter: Wt alias cnt/fill)
__global__ void k_wt2(const float* __restrict__ W1, unsigned short* __restrict__ Wt1,
                      const float* __restrict__ W2, unsigned short* __restrict__ Wt2) {
    int bid = blockIdx.x;
    const float* W = (bid < 64) ? W1 : W2;
    unsigned short* Wt = (bid < 64) ? Wt1 : Wt2;
    int id = (bid & 63) * 256 + threadIdx.x;   // 16384
    int n = id >> 7, k = id & 127;
    Wt[(size_t)n * 128 + k] = f2b(W[(size_t)k * 128 + n]);
}

// ---------------- bf16 MFMA matmul ----------------
// C = A[80000,128] @ W, bf16 out row gm -> Cn + gm*128 ([B,N,128] order, coalesced).
// A-op = Wt tiles (M-dim = feature), B-op = activation rows:
//   D col=lane&15 -> act row; D row=quad*4+reg -> 4 consecutive features/lane.
template <bool ABF16>
__global__ __launch_bounds__(256) void k_mm_mfma(const void* __restrict__ Ap,
                                                 const unsigned short* __restrict__ Wt,
                                                 unsigned short* __restrict__ Cn) {
    __shared__ unsigned short wlds[128 * 136];  // +8 pad (34.8 KB); reused as C-stage
    const int t = threadIdx.x;
    {   // stage Wt (32 KB), 2 threads/row, 64 ushorts each
        const int r = t >> 1, h = t & 1;
        const ushort8* src = (const ushort8*)(Wt + r * 128 + h * 64);
        #pragma unroll
        for (int i = 0; i < 8; i++)
            *(ushort8*)(wlds + r * 136 + h * 64 + i * 8) = src[i];
    }
    __syncthreads();

    const int wid = t >> 6, lane = t & 63;
    const int quad = lane >> 4, l16 = lane & 15;
    const int m0 = blockIdx.x * 128 + (wid & 1) * 64;  // act row base for this wave
    const int nb = (wid >> 1) * 64;                    // feature base
    const int kq = quad * 8;

    f32x4 acc[4][4] = {};

    #pragma unroll
    for (int ks = 0; ks < 128; ks += 32) {
        short8 bf[4];
        #pragma unroll
        for (int mi = 0; mi < 4; mi++) {
            const size_t row = (size_t)(m0 + mi * 16 + l16);
            if constexpr (ABF16) {
                bf[mi] = *(const short8*)((const unsigned short*)Ap + row * 128 + ks + kq);
            } else {
                const float* p = (const float*)Ap + row * 128 + ks + kq;
                float4 u0 = *(const float4*)p;
                float4 u1 = *(const float4*)(p + 4);
                union { uint4 u4; short8 s8; } cv;
                cv.u4.x = f2b2(u0.x, u0.y); cv.u4.y = f2b2(u0.z, u0.w);
                cv.u4.z = f2b2(u1.x, u1.y); cv.u4.w = f2b2(u1.z, u1.w);
                bf[mi] = cv.s8;
            }
        }
        short8 af[4];
        #pragma unroll
        for (int ni = 0; ni < 4; ni++)
            af[ni] = *(const short8*)(wlds + (nb + ni * 16 + l16) * 136 + ks + kq);
        #pragma unroll
        for (int mi = 0; mi < 4; mi++)
            #pragma unroll
            for (int ni = 0; ni < 4; ni++)
                acc[mi][ni] = __builtin_amdgcn_mfma_f32_16x16x32_bf16(
                    af[ni], bf[mi], acc[mi][ni], 0, 0, 0);
    }

    // ---- epilogue: stage 128x128 bf16 tile in LDS, coalesced stores ----
    __syncthreads();  // done reading W tile; reuse wlds
    {
        const int rbase = (wid & 1) * 64;
        #pragma unroll
        for (int mi = 0; mi < 4; mi++) {
            int rr = rbase + mi * 16 + l16;
            #pragma unroll
            for (int ni = 0; ni < 4; ni++) {
                uint2 p;
                p.x = f2b2(acc[mi][ni][0], acc[mi][ni][1]);
                p.y = f2b2(acc[mi][ni][2], acc[mi][ni][3]);
                *(uint2*)(wlds + rr * 136 + nb + ni * 16 + quad * 4) = p;
            }
        }
    }
    __syncthreads();
    {
        const int r = t >> 1, h = t & 1;     // 128 rows x 2 halves of 128 B
        size_t gm = (size_t)blockIdx.x * 128 + r;   // row index in [B,N] order
        unsigned short* dst = Cn + gm * 128 + h * 64;
        const unsigned short* srow = wlds + r * 136 + h * 64;
        #pragma unroll
        for (int i = 0; i < 8; i++)
            *(ushort8*)(dst + i * 8) = *(const ushort8*)(srow + i * 8);
    }
}

// ---------------- aggregation ----------------
// hNu: bf16 [B, N, 128] viewed as uint. One WAVE per (node, batch); lane holds
// feats {2*lane, 2*lane+1}; per edge one 256 B contiguous gather.
// b = blockIdx & 7 -> XCD round-robin; batch b's slice is a CONTIGUOUS 2.56 MB
// region (uniform L2 set usage) + 0.64 MB packed edges -> ~3.2 MB, L2-resident.

__global__ __launch_bounds__(256) void k_agg_relu(const unsigned int* __restrict__ hNu,
                                                  const float* __restrict__ bias,
                                                  const int* __restrict__ row_ptr,
                                                  const unsigned int* __restrict__ edge,
                                                  const float* __restrict__ dinv,
                                                  unsigned int* __restrict__ h1u) {
    const int t = threadIdx.x;
    const int b = blockIdx.x & 7;
    const int g = blockIdx.x >> 3;
    const int wid = __builtin_amdgcn_readfirstlane(t >> 6);
    const int lane = t & 63;
    const int n = g * 4 + wid;

    const unsigned int* base = hNu + (size_t)b * NNODES * 64 + lane;  // + s*64
    float di = dinv[n];
    float wself = di * di;
    unsigned int u = base[(size_t)n * 64];
    float a0 = b2f_lo(u) * wself;
    float a1 = b2f_hi(u) * wself;

    int e = row_ptr[n], e1 = row_ptr[n + 1];
    for (; e + 8 <= e1; e += 8) {
        unsigned int E[8];
        #pragma unroll
        for (int j = 0; j < 8; j++) E[j] = edge[e + j];
        unsigned int U[8];
        #pragma unroll
        for (int j = 0; j < 8; j++) U[j] = base[(size_t)(E[j] & 0xffffu) * 64];
        #pragma unroll
        for (int j = 0; j < 8; j++) {
            float w = b2f_hi(E[j]);
            a0 = fmaf(b2f_lo(U[j]), w, a0);
            a1 = fmaf(b2f_hi(U[j]), w, a1);
        }
    }
    for (; e + 4 <= e1; e += 4) {
        unsigned int E[4];
        #pragma unroll
        for (int j = 0; j < 4; j++) E[j] = edge[e + j];
        unsigned int U[4];
        #pragma unroll
        for (int j = 0; j < 4; j++) U[j] = base[(size_t)(E[j] & 0xffffu) * 64];
        #pragma unroll
        for (int j = 0; j < 4; j++) {
            float w = b2f_hi(E[j]);
            a0 = fmaf(b2f_lo(U[j]), w, a0);
            a1 = fmaf(b2f_hi(U[j]), w, a1);
        }
    }
    for (; e < e1; ++e) {
        unsigned int E = edge[e];
        float w = b2f_hi(E);
        unsigned int uu = base[(size_t)(E & 0xffffu) * 64];
        a0 = fmaf(b2f_lo(uu), w, a0);
        a1 = fmaf(b2f_hi(uu), w, a1);
    }
    a0 = fmaxf(a0 + bias[lane * 2], 0.f);
    a1 = fmaxf(a1 + bias[lane * 2 + 1], 0.f);
    __builtin_nontemporal_store(f2b2(a0, a1), &h1u[((size_t)b * NNODES + n) * 64 + lane]);
}

__global__ __launch_bounds__(256) void k_agg_ln(const unsigned int* __restrict__ hNu,
                                                const float* __restrict__ bias,
                                                const int* __restrict__ row_ptr,
                                                const unsigned int* __restrict__ edge,
                                                const float* __restrict__ dinv,
                                                const float* __restrict__ ln_w,
                                                const float* __restrict__ ln_b,
                                                float* __restrict__ out) {
    const int t = threadIdx.x;
    const int b = blockIdx.x & 7;
    const int g = blockIdx.x >> 3;
    const int wid = __builtin_amdgcn_readfirstlane(t >> 6);
    const int lane = t & 63;
    const int n = g * 4 + wid;

    const unsigned int* base = hNu + (size_t)b * NNODES * 64 + lane;
    float di = dinv[n];
    float wself = di * di;
    unsigned int u = base[(size_t)n * 64];
    float a0 = b2f_lo(u) * wself;
    float a1 = b2f_hi(u) * wself;

    int e = row_ptr[n], e1 = row_ptr[n + 1];
    for (; e + 8 <= e1; e += 8) {
        unsigned int E[8];
        #pragma unroll
        for (int j = 0; j < 8; j++) E[j] = edge[e + j];
        unsigned int U[8];
        #pragma unroll
        for (int j = 0; j < 8; j++) U[j] = base[(size_t)(E[j] & 0xffffu) * 64];
        #pragma unroll
        for (int j = 0; j < 8; j++) {
            float w = b2f_hi(E[j]);
            a0 = fmaf(b2f_lo(U[j]), w, a0);
            a1 = fmaf(b2f_hi(U[j]), w, a1);
        }
    }
    for (; e + 4 <= e1; e += 4) {
        unsigned int E[4];
        #pragma unroll
        for (int j = 0; j < 4; j++) E[j] = edge[e + j];
        unsigned int U[4];
        #pragma unroll
        for (int j = 0; j < 4; j++) U[j] = base[(size_t)(E[j] & 0xffffu) * 64];
        #pragma unroll
        for (int j = 0; j < 4; j++) {
            float w = b2f_hi(E[j]);
            a0 = fmaf(b2f_lo(U[j]), w, a0);
            a1 = fmaf(b2f_hi(U[j]), w, a1);
        }
    }
    for (; e < e1; ++e) {
        unsigned int E = edge[e];
        float w = b2f_hi(E);
        unsigned int uu = base[(size_t)(E & 0xffffu) * 64];
        a0 = fmaf(b2f_lo(uu), w, a0);
        a1 = fmaf(b2f_hi(uu), w, a1);
    }
    a0 += bias[lane * 2];
    a1 += bias[lane * 2 + 1];

    // LayerNorm over 128 feats spread across the 64-lane wave (2/lane)
    float s1 = a0 + a1;
    float s2 = a0 * a0 + a1 * a1;
    #pragma unroll
    for (int m = 1; m < 64; m <<= 1) {
        s1 += __shfl_xor(s1, m);
        s2 += __shfl_xor(s2, m);
    }
    float mu = s1 * (1.f / NF);
    float var = s2 * (1.f / NF) - mu * mu;
    float rs = rsqrtf(var + 1e-5f);

    float o0 = (a0 - mu) * rs * ln_w[lane * 2] + ln_b[lane * 2];
    float o1 = (a1 - mu) * rs * ln_w[lane * 2 + 1] + ln_b[lane * 2 + 1];
    float* dst = out + ((size_t)b * NNODES + n) * 128 + lane * 2;
    __builtin_nontemporal_store(o0, dst);
    __builtin_nontemporal_store(o1, dst + 1);
}

// ---------------- launch ----------------

extern "C" void kernel_launch(void* const* d_in, const int* in_sizes, int n_in,
                              void* d_out, int out_size, void* d_ws, size_t ws_size,
                              hipStream_t stream) {
    const float* x    = (const float*)d_in[0];
    const int*   ei   = (const int*)d_in[1];   // int32 [2, E]
    const float* W1   = (const float*)d_in[2];
    const float* b1   = (const float*)d_in[3];
    const float* W2   = (const float*)d_in[4];
    const float* b2   = (const float*)d_in[5];
    const float* ln_w = (const float*)d_in[6];
    const float* ln_b = (const float*)d_in[7];
    float* out = (float*)d_out;

    // workspace layout. Wt1/Wt2 alias cnt/fill (dead after scan/scatter; k_wt2 runs after).
    char* ws = (char*)d_ws;
    int*            cnt     = (int*)(ws + 0);          // N ints; later Wt1 (32 KB)
    int*            fill    = (int*)(ws + 40192);      // N ints; later Wt2 (32 KB)
    int*            row_ptr = (int*)(ws + 80384);      // N+1 ints
    float*          dinv    = (float*)(ws + 120832);   // N floats
    unsigned int*   edge    = (unsigned int*)(ws + 161024);     // E uint (640 KB)
    unsigned short* hA16    = (unsigned short*)(ws + 1441024);  // [B,N,128] bf16 (20.48 MB)
    unsigned short* h1b     = (unsigned short*)(ws + 21921024); // [B,N,128] bf16 (20.48 MB)
    unsigned short* Wt1     = (unsigned short*)cnt;
    unsigned short* Wt2     = (unsigned short*)fill;

    // ---- CSR (by dst) + symmetric norm weights ----
    k_zero   <<<(2 * NNODES + 255) / 256, 256, 0, stream>>>(cnt, fill);
    k_count  <<<(NE + 255) / 256, 256, 0, stream>>>(ei, cnt);
    k_scan   <<<1, 1024, 0, stream>>>(cnt, row_ptr, dinv);
    k_scatter<<<(NE + 255) / 256, 256, 0, stream>>>(ei, row_ptr, fill, dinv, edge);
    k_wt2    <<<128, 256, 0, stream>>>(W1, Wt1, W2, Wt2);

    // ---- layer 1 ----
    k_mm_mfma<false><<<(NB * NNODES) / 128, 256, 0, stream>>>(x, Wt1, hA16);
    k_agg_relu<<<(NNODES / 4) * NB, 256, 0, stream>>>((const unsigned int*)hA16, b1,
                                                      row_ptr, edge, dinv,
                                                      (unsigned int*)h1b);

    // ---- layer 2 ----
    k_mm_mfma<true><<<(NB * NNODES) / 128, 256, 0, stream>>>(h1b, Wt2, hA16);
    k_agg_ln<<<(NNODES / 4) * NB, 256, 0, stream>>>((const unsigned int*)hA16, b2,
                                                    row_ptr, edge, dinv,
                                                    ln_w, ln_b, out);
}